// Round 4
// baseline (4895.494 us; speedup 1.0000x reference)
//
#include <hip/hip_runtime.h>
#include <hip/hip_bf16.h>

// ZambaMambaMixer: B=2,S=2048,H=2048,EXPAND=2 -> I=4096, N=16,K=4,R=128,NH=2,
// HD=2048, RN=160.
// Dtype model (T3, confirmed by rounds 0-3 forensics): ALL inputs fp32,
// OUTPUT fp32 (contract: dtype follows reference). Intermediates bf16 in ws.
// ws budget: R1 proved ws_size < 274 MB; R3 ran 139.5 MB without fault.
// This round uses 105.9 MB ws + parks dt scratch inside d_out (exact fit,
// lifetime ends before the final out_proj write).
#define BB   2
#define SS   2048
#define HH   2048
#define II   4096
#define NHH  2
#define HDD  2048
#define NNS  16
#define RR   128
#define RN2  160
#define BSF  (BB*SS)   // 4096 flattened (b,s) rows

typedef __hip_bfloat16 bf16;

__device__ inline float b2f(bf16 v) { return __bfloat162float(v); }
__device__ inline bf16  f2b(float v) { return __float2bfloat16(v); }

__device__ inline void  stx(float* p, float v) { *p = v; }
__device__ inline void  stx(bf16* p, float v)  { *p = __float2bfloat16(v); }

// 4-element vector load -> fp32 (16B-aligned for float, 8B for bf16)
__device__ inline void load4(const float* p, float v[4]) {
    float4 t = *(const float4*)p;
    v[0] = t.x; v[1] = t.y; v[2] = t.z; v[3] = t.w;
}
__device__ inline void load4(const bf16* p, float v[4]) {
    union { ushort4 u; bf16 h[4]; } t;
    t.u = *(const ushort4*)p;
    v[0] = b2f(t.h[0]); v[1] = b2f(t.h[1]); v[2] = b2f(t.h[2]); v[3] = b2f(t.h[3]);
}

// ---------------------------------------------------------------------------
// Big NT GEMM (fp32 acc): C[m][n] = sum_k A[m][k]*B[n][k]
// 128x128 tile, BK=8, 256 threads, 8x8 micro-tile.
// MODE 0: de-interleave even/odd n into C0 (x) / C1 (gate) at col n/2 (TC=bf16)
// MODE 1: plain row-major store into C0 (TC=float)
// ---------------------------------------------------------------------------
template <int MODE, typename TA, typename TB, typename TC>
__global__ __launch_bounds__(256) void gemm_big(
    const TA* __restrict__ A, const TB* __restrict__ B,
    TC* __restrict__ C0, TC* __restrict__ C1,
    int Kd, int lda, int ldb, int ldc)
{
    __shared__ float As[8][132];
    __shared__ float Bs[8][132];
    const int tid  = threadIdx.x;
    const int mt   = blockIdx.y, nt = blockIdx.x;
    const int arow = tid >> 1;           // 0..127
    const int ak4  = (tid & 1) * 4;      // 0 or 4
    const TA* Aptr = A + (long)(mt * 128 + arow) * lda + ak4;
    const TB* Bptr = B + (long)(nt * 128 + arow) * ldb + ak4;
    const int tx = tid & 15, ty = tid >> 4;

    float acc[8][8];
#pragma unroll
    for (int i = 0; i < 8; ++i)
#pragma unroll
        for (int j = 0; j < 8; ++j) acc[i][j] = 0.f;

    for (int kt = 0; kt < Kd; kt += 8) {
        float av[4], bv[4];
        load4(Aptr + kt, av);
        load4(Bptr + kt, bv);
        __syncthreads();
#pragma unroll
        for (int j = 0; j < 4; ++j) {
            As[ak4 + j][arow] = av[j];
            Bs[ak4 + j][arow] = bv[j];
        }
        __syncthreads();
#pragma unroll
        for (int k = 0; k < 8; ++k) {
            float4 a0 = *(const float4*)&As[k][ty * 8];
            float4 a1 = *(const float4*)&As[k][ty * 8 + 4];
            float4 b0 = *(const float4*)&Bs[k][tx * 8];
            float4 b1 = *(const float4*)&Bs[k][tx * 8 + 4];
            float a[8] = {a0.x, a0.y, a0.z, a0.w, a1.x, a1.y, a1.z, a1.w};
            float b[8] = {b0.x, b0.y, b0.z, b0.w, b1.x, b1.y, b1.z, b1.w};
#pragma unroll
            for (int im = 0; im < 8; ++im)
#pragma unroll
                for (int in = 0; in < 8; ++in)
                    acc[im][in] = fmaf(a[im], b[in], acc[im][in]);
        }
    }

    const int n0g = nt * 128 + tx * 8;
#pragma unroll
    for (int im = 0; im < 8; ++im) {
        const int m = mt * 128 + ty * 8 + im;
        if (MODE == 0) {
            // n = o index; even o -> x (i=o/2), odd o -> gate  (TC = bf16)
            union { bf16 h[4]; uint2 u; } ev, od;
#pragma unroll
            for (int j = 0; j < 4; ++j) {
                ev.h[j] = f2b(acc[im][2 * j]);
                od.h[j] = f2b(acc[im][2 * j + 1]);
            }
            const int i0 = n0g >> 1;  // multiple of 4 -> 8B aligned
            *(uint2*)((bf16*)C0 + (long)m * ldc + i0) = ev.u;
            *(uint2*)((bf16*)C1 + (long)m * ldc + i0) = od.u;
        } else {
            // TC = float: two float4 stores
            *(float4*)((float*)C0 + (long)m * ldc + n0g) =
                make_float4(acc[im][0], acc[im][1], acc[im][2], acc[im][3]);
            *(float4*)((float*)C0 + (long)m * ldc + n0g + 4) =
                make_float4(acc[im][4], acc[im][5], acc[im][6], acc[im][7]);
        }
    }
}

// ---------------------------------------------------------------------------
// Depthwise causal conv (K=4) + bias + SiLU. Layout (b*s, i), i contiguous.
// ---------------------------------------------------------------------------
__global__ __launch_bounds__(256) void conv_silu_kernel(
    const bf16* __restrict__ xraw, const float* __restrict__ conv_w,
    const float* __restrict__ conv_b, bf16* __restrict__ xs)
{
    const int idx = blockIdx.x * 256 + threadIdx.x;  // over BSF*II
    const int i  = idx & (II - 1);
    const int bs = idx >> 12;          // II = 4096 = 2^12
    const int s  = bs & (SS - 1);
    const float4 cw = ((const float4*)conv_w)[i];
    float v = conv_b[i];
    const bf16* col = xraw + (long)bs * II + i;
    if (s >= 3) v = fmaf(b2f(col[-3 * II]), cw.x, v);
    if (s >= 2) v = fmaf(b2f(col[-2 * II]), cw.y, v);
    if (s >= 1) v = fmaf(b2f(col[-1 * II]), cw.z, v);
    v = fmaf(b2f(col[0]), cw.w, v);
    stx(&xs[idx], v / (1.f + __expf(-v)));
}

// ---------------------------------------------------------------------------
// Small NT GEMM, transposed store C[n*ldc+m], optional fp32-bias+softplus.
// 64x64 tile, BK=16, 256 threads, 4x4 micro-tile. blockIdx.z = head h.
// ---------------------------------------------------------------------------
template <typename TA, typename TB, typename TC, int SOFTPLUS>
__global__ __launch_bounds__(256) void gemm_small(
    const TA* __restrict__ A, int lda, long hstrA,
    const TB* __restrict__ B, int ldb, long hstrB,
    TC* __restrict__ C, int ldc, long hstrC,
    const float* __restrict__ bias, long hstrBias,
    int M, int Kd)
{
    const int h = blockIdx.z;
    A += h * hstrA; B += h * hstrB; C += h * hstrC;
    if (SOFTPLUS) bias += h * hstrBias;
    __shared__ float As[16][68];
    __shared__ float Bs[16][68];
    const int tid = threadIdx.x;
    const int row = tid >> 2, k4 = (tid & 3) * 4;
    const int mt = blockIdx.y, nt = blockIdx.x;
    const int am = mt * 64 + row;
    const bool avalid = (am < M);
    const TA* Aptr = A + (long)am * lda + k4;
    const TB* Bptr = B + (long)(nt * 64 + row) * ldb + k4;
    const int tm = tid & 15, tn = tid >> 4;

    float acc[4][4];
#pragma unroll
    for (int i = 0; i < 4; ++i)
#pragma unroll
        for (int j = 0; j < 4; ++j) acc[i][j] = 0.f;

    for (int kt = 0; kt < Kd; kt += 16) {
        float av[4] = {0.f, 0.f, 0.f, 0.f}, bv[4];
        if (avalid) load4(Aptr + kt, av);
        load4(Bptr + kt, bv);
        __syncthreads();
#pragma unroll
        for (int j = 0; j < 4; ++j) {
            As[k4 + j][row] = av[j];
            Bs[k4 + j][row] = bv[j];
        }
        __syncthreads();
#pragma unroll
        for (int k = 0; k < 16; ++k) {
            float4 a4 = *(const float4*)&As[k][tm * 4];
            float4 b4 = *(const float4*)&Bs[k][tn * 4];
            float a[4] = {a4.x, a4.y, a4.z, a4.w};
            float b[4] = {b4.x, b4.y, b4.z, b4.w};
#pragma unroll
            for (int im = 0; im < 4; ++im)
#pragma unroll
                for (int in = 0; in < 4; ++in)
                    acc[im][in] = fmaf(a[im], b[in], acc[im][in]);
        }
    }

#pragma unroll
    for (int in = 0; in < 4; ++in) {
        const int n = nt * 64 + tn * 4 + in;
#pragma unroll
        for (int im = 0; im < 4; ++im) {
            const int m = mt * 64 + tm * 4 + im;
            if (m < M) {
                float v = acc[im][in];
                if (SOFTPLUS) {
                    v += bias[m];
                    v = (v > 20.f) ? v : log1pf(__expf(v));
                }
                stx(&C[(long)n * ldc + m], v);
            }
        }
    }
}

// ---------------------------------------------------------------------------
// Selective scan fused with D-skip and SiLU gating.
// One thread per (h,b,d,n); 16 n-lanes per channel reduce via shfl_xor.
// ---------------------------------------------------------------------------
__global__ __launch_bounds__(256) void scan_kernel(
    const bf16* __restrict__ dtb, const bf16* __restrict__ xs,
    const bf16* __restrict__ gate, const float* __restrict__ ssm,
    const float* __restrict__ A_log, const float* __restrict__ Dp,
    bf16* __restrict__ yfin)
{
    const int tid = threadIdx.x;
    const int n = tid & 15, dl = tid >> 4;
    const int blk = blockIdx.x;          // NHH*BB*(HDD/16) = 512
    const int dchunk = blk & 127;        // HDD/16 = 128
    const int hb = blk >> 7;             // 0..3
    const int b = hb & 1, h = hb >> 1;
    const int d = dchunk * 16 + dl;
    const int i = h * HDD + d;

    const float Aval = -__expf(A_log[(long)i * NNS + n]);
    const float Dv = Dp[i];
    long p = (long)b * SS * II + i;
    long q = ((long)h * BSF + (long)b * SS) * RN2;
    float st = 0.f;

    for (int t = 0; t < SS; ++t) {
        const float dtv = b2f(dtb[p]);
        const float xv  = b2f(xs[p]);
        const float gv  = b2f(gate[p]);
        const float Bv  = ssm[q + RR + n];
        const float Cv  = ssm[q + RR + NNS + n];
        const float dA  = __expf(Aval * dtv);
        st = fmaf(dA, st, dtv * Bv * xv);
        float y = st * Cv;
        y += __shfl_xor(y, 1);
        y += __shfl_xor(y, 2);
        y += __shfl_xor(y, 4);
        y += __shfl_xor(y, 8);
        if (n == 0) {
            const float yy = y + xv * Dv;
            const float sg = gv / (1.f + __expf(-gv));
            yfin[p] = f2b(yy * sg);
        }
        p += II;
        q += RN2;
    }
}

// ---------------------------------------------------------------------------
extern "C" void kernel_launch(void* const* d_in, const int* in_sizes, int n_in,
                              void* d_out, int out_size, void* d_ws, size_t ws_size,
                              hipStream_t stream) {
    const float* hidden     = (const float*)d_in[0];
    const float* in_proj_w  = (const float*)d_in[1];
    const float* conv_w     = (const float*)d_in[2];
    const float* conv_b     = (const float*)d_in[3];
    const float* x_proj_w   = (const float*)d_in[4];
    const float* dt_proj_w  = (const float*)d_in[5];
    const float* dt_proj_b  = (const float*)d_in[6];
    const float* A_log      = (const float*)d_in[7];
    const float* Dp         = (const float*)d_in[8];
    const float* out_proj_w = (const float*)d_in[9];
    float* out = (float*)d_out;

    const long NBI = (long)BSF * II;      // 16,777,216 elems per activation buf
    bf16* wsb  = (bf16*)d_ws;
    bf16* xraw = wsb;                     // pre-conv x   (b*s, i)   bf16 33.5MB
    bf16* gate = wsb + NBI;               // gate         (b*s, i)   bf16 33.5MB
    bf16* xsb  = wsb + 2 * NBI;           // conv+silu x  (b*s, i)   bf16 33.5MB
    float* ssm = (float*)(wsb + 3 * NBI); // ssm_p        (h,b*s,160) fp32 5.2MB
    bf16* yfin = xraw;                    // reuse xraw after conv
    // dt scratch parked in d_out (exactly out_size*4 bytes = BSF*II bf16);
    // written step 4, read step 5, overwritten by final out at step 6.
    bf16* dtb  = (bf16*)d_out;

    // 1) in_proj: C[(b,s)][o] = hidden . in_proj_w^T, de-interleave even/odd o
    gemm_big<0, float, float, bf16><<<dim3(8192 / 128, BSF / 128), 256, 0, stream>>>(
        hidden, in_proj_w, xraw, gate, HH, HH, HH, II);

    // 2) depthwise causal conv + SiLU
    conv_silu_kernel<<<(BSF * II) / 256, 256, 0, stream>>>(xraw, conv_w, conv_b, xsb);

    // 3) x_proj: ssm[h][(b,s)][r] = x_proj_w[h] . xs[h]^T  (M=160, K=2048)
    gemm_small<float, bf16, float, 0><<<dim3(BSF / 64, 3, NHH), 256, 0, stream>>>(
        x_proj_w, HDD, (long)RN2 * HDD,
        xsb, II, (long)HDD,
        ssm, RN2, (long)BSF * RN2,
        nullptr, 0, RN2, HDD);

    // 4) dt: dtb[(b,s)][h*HD+d] = softplus(dt_proj_w[h] . dt_in + bias)
    gemm_small<float, float, bf16, 1><<<dim3(BSF / 64, HDD / 64, NHH), 256, 0, stream>>>(
        dt_proj_w, RR, (long)HDD * RR,
        ssm, RN2, (long)BSF * RN2,
        dtb, II, (long)HDD,
        dt_proj_b, (long)HDD,
        HDD, RR);

    // 5) selective scan + D skip + SiLU gating -> yfin (b*s, i)
    scan_kernel<<<NHH * BB * (HDD / 16), 256, 0, stream>>>(
        dtb, xsb, gate, ssm, A_log, Dp, yfin);

    // 6) out_proj: out[(b,s)][h'] = yfin . out_proj_w^T  (fp32 store)
    gemm_big<1, bf16, float, float><<<dim3(HH / 128, BSF / 128), 256, 0, stream>>>(
        yfin, out_proj_w, out, nullptr, II, II, II, HH);
}

// Round 5
// 1542.648 us; speedup vs baseline: 3.1734x; 3.1734x over previous
//
#include <hip/hip_runtime.h>
#include <hip/hip_bf16.h>

// ZambaMambaMixer: B=2,S=2048,H=2048 -> I=4096, N=16,K=4,R=128,NH=2,HD=2048.
// Dtype model T3 (confirmed R4): inputs fp32, output fp32. Intermediates bf16.
// R5: bf16-MFMA big GEMMs (m97 structure + XOR swizzle) + coalesced scan.
#define BB   2
#define SS   2048
#define HH   2048
#define II   4096
#define NHH  2
#define HDD  2048
#define NNS  16
#define RR   128
#define RN2  160
#define BSF  (BB*SS)   // 4096

typedef __hip_bfloat16 bf16;
typedef __attribute__((ext_vector_type(8))) short short8;
typedef __attribute__((ext_vector_type(4))) float floatx4;

__device__ inline float b2f(bf16 v) { return __bfloat162float(v); }
__device__ inline bf16  f2b(float v) { return __float2bfloat16(v); }

__device__ inline void  stx(float* p, float v) { *p = v; }
__device__ inline void  stx(bf16* p, float v)  { *p = __float2bfloat16(v); }

__device__ inline void load4(const float* p, float v[4]) {
    float4 t = *(const float4*)p;
    v[0] = t.x; v[1] = t.y; v[2] = t.z; v[3] = t.w;
}
__device__ inline void load4(const bf16* p, float v[4]) {
    union { ushort4 u; bf16 h[4]; } t;
    t.u = *(const ushort4*)p;
    v[0] = b2f(t.h[0]); v[1] = b2f(t.h[1]); v[2] = b2f(t.h[2]); v[3] = b2f(t.h[3]);
}

// async global->LDS, 16B per lane, lane L lands at ldsbase + L*16
__device__ inline void load_lds16(const bf16* g, short* l) {
    __builtin_amdgcn_global_load_lds(
        (const __attribute__((address_space(1))) void*)g,
        (__attribute__((address_space(3))) void*)l, 16, 0, 0);
}

// ---------------------------------------------------------------------------
// fp32 -> bf16 cast, 4 elems/thread
// ---------------------------------------------------------------------------
__global__ __launch_bounds__(256) void cast_f2b(
    const float* __restrict__ src, bf16* __restrict__ dst)
{
    const int idx = blockIdx.x * 256 + threadIdx.x;
    float4 v = ((const float4*)src)[idx];
    union { bf16 h[4]; uint2 u; } o;
    o.h[0] = f2b(v.x); o.h[1] = f2b(v.y); o.h[2] = f2b(v.z); o.h[3] = f2b(v.w);
    ((uint2*)dst)[idx] = o.u;
}

// ---------------------------------------------------------------------------
// MFMA NT GEMM (bf16 x bf16, fp32 acc): C[m][n] = sum_k A[m][k]*B[n][k]
// 128x128 tile, BK=32, 256 thr = 4 waves (2x2 of 64x64), 16x16x32 MFMA.
// global_load_lds(16B) staging; XOR swizzle on k-chunks kills bank conflicts.
// MODE 0: n even -> C0 (x), n odd -> C1 (gate) bf16 at col n/2, ldc=II
// MODE 1: fp32 row-major store to C0
// ---------------------------------------------------------------------------
template <int MODE>
__global__ __launch_bounds__(256) void gemm_mfma(
    const bf16* __restrict__ A, const bf16* __restrict__ B,
    void* __restrict__ C0v, void* __restrict__ C1v, int Kd, int ldc)
{
    __shared__ short Asm[128 * 32];
    __shared__ short Bsm[128 * 32];
    const int tid  = threadIdx.x;
    const int wave = tid >> 6, lane = tid & 63;
    const int wr = wave >> 1, wc = wave & 1;
    const int mt = blockIdx.y, nt = blockIdx.x;
    const int rl = lane >> 2, slot = lane & 3;      // staging: 16 rows/instr
    const int gchunk = slot ^ (rl & 3);             // global k-chunk swizzle
    const int l15 = lane & 15, l4 = lane >> 4;

    floatx4 acc[4][4];
#pragma unroll
    for (int i = 0; i < 4; ++i)
#pragma unroll
        for (int j = 0; j < 4; ++j) acc[i][j] = (floatx4){0.f, 0.f, 0.f, 0.f};

    const long ldk = Kd;
    for (int kt = 0; kt < Kd; kt += 32) {
#pragma unroll
        for (int half = 0; half < 2; ++half) {
            const int row = wave * 32 + half * 16 + rl;
            load_lds16(A + (long)(mt * 128 + row) * ldk + kt + gchunk * 8,
                       Asm + (wave * 32 + half * 16) * 32);
            load_lds16(B + (long)(nt * 128 + row) * ldk + kt + gchunk * 8,
                       Bsm + (wave * 32 + half * 16) * 32);
        }
        __syncthreads();
        short8 af[4], bf[4];
#pragma unroll
        for (int f = 0; f < 4; ++f) {
            const int ra = wr * 64 + f * 16 + l15;
            const int rb = wc * 64 + f * 16 + l15;
            af[f] = *(const short8*)(Asm + ra * 32 + ((l4 ^ (ra & 3)) * 8));
            bf[f] = *(const short8*)(Bsm + rb * 32 + ((l4 ^ (rb & 3)) * 8));
        }
#pragma unroll
        for (int fm = 0; fm < 4; ++fm)
#pragma unroll
            for (int fn = 0; fn < 4; ++fn)
                acc[fm][fn] = __builtin_amdgcn_mfma_f32_16x16x32_bf16(
                    af[fm], bf[fn], acc[fm][fn], 0, 0, 0);
        __syncthreads();
    }

#pragma unroll
    for (int fm = 0; fm < 4; ++fm)
#pragma unroll
        for (int fn = 0; fn < 4; ++fn) {
            const int gcol = nt * 128 + wc * 64 + fn * 16 + l15;
#pragma unroll
            for (int r = 0; r < 4; ++r) {
                const int grow = mt * 128 + wr * 64 + fm * 16 + l4 * 4 + r;
                const float v = acc[fm][fn][r];
                if (MODE == 0) {
                    bf16* buf = (gcol & 1) ? (bf16*)C1v : (bf16*)C0v;
                    buf[(long)grow * ldc + (gcol >> 1)] = f2b(v);
                } else {
                    ((float*)C0v)[(long)grow * ldc + gcol] = v;
                }
            }
        }
}

// ---------------------------------------------------------------------------
// Depthwise causal conv (K=4) + bias + SiLU. Layout (b*s, i), i contiguous.
// ---------------------------------------------------------------------------
__global__ __launch_bounds__(256) void conv_silu_kernel(
    const bf16* __restrict__ xraw, const float* __restrict__ conv_w,
    const float* __restrict__ conv_b, bf16* __restrict__ xs)
{
    const int idx = blockIdx.x * 256 + threadIdx.x;  // over BSF*II
    const int i  = idx & (II - 1);
    const int bs = idx >> 12;
    const int s  = bs & (SS - 1);
    const float4 cw = ((const float4*)conv_w)[i];
    float v = conv_b[i];
    const bf16* col = xraw + (long)bs * II + i;
    if (s >= 3) v = fmaf(b2f(col[-3 * II]), cw.x, v);
    if (s >= 2) v = fmaf(b2f(col[-2 * II]), cw.y, v);
    if (s >= 1) v = fmaf(b2f(col[-1 * II]), cw.z, v);
    v = fmaf(b2f(col[0]), cw.w, v);
    stx(&xs[idx], v / (1.f + __expf(-v)));
}

// ---------------------------------------------------------------------------
// Small NT GEMM, transposed store C[n*ldc+m], optional fp32-bias+softplus.
// 64x64 tile, BK=16, 256 threads, 4x4 micro-tile. blockIdx.z = head h.
// ---------------------------------------------------------------------------
template <typename TA, typename TB, typename TC, int SOFTPLUS>
__global__ __launch_bounds__(256) void gemm_small(
    const TA* __restrict__ A, int lda, long hstrA,
    const TB* __restrict__ B, int ldb, long hstrB,
    TC* __restrict__ C, int ldc, long hstrC,
    const float* __restrict__ bias, long hstrBias,
    int M, int Kd)
{
    const int h = blockIdx.z;
    A += h * hstrA; B += h * hstrB; C += h * hstrC;
    if (SOFTPLUS) bias += h * hstrBias;
    __shared__ float As[16][68];
    __shared__ float Bs[16][68];
    const int tid = threadIdx.x;
    const int row = tid >> 2, k4 = (tid & 3) * 4;
    const int mt = blockIdx.y, nt = blockIdx.x;
    const int am = mt * 64 + row;
    const bool avalid = (am < M);
    const TA* Aptr = A + (long)am * lda + k4;
    const TB* Bptr = B + (long)(nt * 64 + row) * ldb + k4;
    const int tm = tid & 15, tn = tid >> 4;

    float acc[4][4];
#pragma unroll
    for (int i = 0; i < 4; ++i)
#pragma unroll
        for (int j = 0; j < 4; ++j) acc[i][j] = 0.f;

    for (int kt = 0; kt < Kd; kt += 16) {
        float av[4] = {0.f, 0.f, 0.f, 0.f}, bv[4];
        if (avalid) load4(Aptr + kt, av);
        load4(Bptr + kt, bv);
        __syncthreads();
#pragma unroll
        for (int j = 0; j < 4; ++j) {
            As[k4 + j][row] = av[j];
            Bs[k4 + j][row] = bv[j];
        }
        __syncthreads();
#pragma unroll
        for (int k = 0; k < 16; ++k) {
            float4 a4 = *(const float4*)&As[k][tm * 4];
            float4 b4 = *(const float4*)&Bs[k][tn * 4];
            float a[4] = {a4.x, a4.y, a4.z, a4.w};
            float b[4] = {b4.x, b4.y, b4.z, b4.w};
#pragma unroll
            for (int im = 0; im < 4; ++im)
#pragma unroll
                for (int in = 0; in < 4; ++in)
                    acc[im][in] = fmaf(a[im], b[in], acc[im][in]);
        }
    }

#pragma unroll
    for (int in = 0; in < 4; ++in) {
        const int n = nt * 64 + tn * 4 + in;
#pragma unroll
        for (int im = 0; im < 4; ++im) {
            const int m = mt * 64 + tm * 4 + im;
            if (m < M) {
                float v = acc[im][in];
                if (SOFTPLUS) {
                    v += bias[m];
                    v = (v > 20.f) ? v : log1pf(__expf(v));
                }
                stx(&C[(long)n * ldc + m], v);
            }
        }
    }
}

// ---------------------------------------------------------------------------
// Coalesced selective scan + D-skip + SiLU gating.
// Thread <-> channel d (256 consecutive per block); 16 n-states in registers;
// B/C staged per-64-t chunk in LDS; 1-deep register prefetch of dt/x/gate.
// Grid: 32 blocks = (h,b) x 8 d-blocks.
// ---------------------------------------------------------------------------
__global__ __launch_bounds__(256) void scan_kernel(
    const bf16* __restrict__ dtb, const bf16* __restrict__ xs,
    const bf16* __restrict__ gate, const float* __restrict__ ssm,
    const float* __restrict__ A_log, const float* __restrict__ Dp,
    bf16* __restrict__ yfin)
{
    __shared__ float Bs[64][16];
    __shared__ float Cs[64][16];
    const int tid = threadIdx.x;
    const int bx = blockIdx.x;
    const int hb = bx >> 3, dblk = bx & 7;
    const int h = hb >> 1, b = hb & 1;
    const int d = dblk * 256 + tid;
    const int i = h * HDD + d;

    float st[16], Aval[16];
#pragma unroll
    for (int n = 0; n < 16; ++n) {
        Aval[n] = -__expf(A_log[(long)i * NNS + n]);
        st[n] = 0.f;
    }
    const float Dv = Dp[i];
    const long rowbase = (long)h * BSF + (long)b * SS;   // ssm row index
    long pcur = ((long)b * SS) * II + i;

    bf16 dt_c = dtb[pcur], x_c = xs[pcur], g_c = gate[pcur];

    const int sr = tid >> 2, sq = tid & 3;               // staging map
    for (int tc = 0; tc < SS; tc += 64) {
        __syncthreads();
        {
            const float* src = ssm + (rowbase + tc + sr) * RN2 + RR + sq * 4;
            float4 bb = *(const float4*)src;
            float4 cc = *(const float4*)(src + 16);
            *(float4*)&Bs[sr][sq * 4] = bb;
            *(float4*)&Cs[sr][sq * 4] = cc;
        }
        __syncthreads();
        for (int tl = 0; tl < 64; ++tl) {
            const int t = tc + tl;
            const long pnext = pcur + II;
            const long pf = (t < SS - 1) ? pnext : pcur;
            bf16 dt_n = dtb[pf], x_n = xs[pf], g_n = gate[pf];

            const float dtv = b2f(dt_c);
            const float xv  = b2f(x_c);
            const float gv  = b2f(g_c);
            const float dtx = dtv * xv;
            float fB[16], fC[16];
#pragma unroll
            for (int j = 0; j < 4; ++j) {
                *(float4*)&fB[j * 4] = *(const float4*)&Bs[tl][j * 4];
                *(float4*)&fC[j * 4] = *(const float4*)&Cs[tl][j * 4];
            }
            float y = 0.f;
#pragma unroll
            for (int n = 0; n < 16; ++n) {
                const float dA = __expf(Aval[n] * dtv);
                st[n] = fmaf(dA, st[n], dtx * fB[n]);
                y = fmaf(st[n], fC[n], y);
            }
            const float sg = gv / (1.f + __expf(-gv));
            yfin[pcur] = f2b((y + xv * Dv) * sg);

            pcur = pnext;
            dt_c = dt_n; x_c = x_n; g_c = g_n;
        }
    }
}

// ---------------------------------------------------------------------------
extern "C" void kernel_launch(void* const* d_in, const int* in_sizes, int n_in,
                              void* d_out, int out_size, void* d_ws, size_t ws_size,
                              hipStream_t stream) {
    const float* hidden     = (const float*)d_in[0];
    const float* in_proj_w  = (const float*)d_in[1];
    const float* conv_w     = (const float*)d_in[2];
    const float* conv_b     = (const float*)d_in[3];
    const float* x_proj_w   = (const float*)d_in[4];
    const float* dt_proj_w  = (const float*)d_in[5];
    const float* dt_proj_b  = (const float*)d_in[6];
    const float* A_log      = (const float*)d_in[7];
    const float* Dp         = (const float*)d_in[8];
    const float* out_proj_w = (const float*)d_in[9];
    float* out = (float*)d_out;

    const long NBI = (long)BSF * II;      // 16,777,216
    // ws (139.4 MB, proven-safe footprint):
    bf16* wsb   = (bf16*)d_ws;
    bf16* inw_bf  = wsb;                  // [0, 16.8M) : in_proj_w bf16, 33.5MB
    bf16* outw_bf = wsb;                  //   reused after step 2 (16.8MB used)
    bf16* xraw  = wsb + NBI;              // pre-conv x  (b*s,i) 33.5MB
    bf16* gate  = wsb + 2 * NBI;          // gate        (b*s,i) 33.5MB
    bf16* xsb   = wsb + 3 * NBI;          // conv+silu x (b*s,i) 33.5MB
    float* ssm  = (float*)(wsb + 4 * NBI);// ssm_p (h,b*s,160) fp32 5.2MB
    bf16* yfin  = xraw;                   // reuse xraw after conv
    // parked in d_out (33.5MB): hidden_bf (16.8MB, dead after step 2),
    // then dtb (33.5MB, written step 6, dead after scan), then final out.
    bf16* hidden_bf = (bf16*)d_out;
    bf16* dtb       = (bf16*)d_out;

    // 1) casts needed for in_proj
    cast_f2b<<<(BSF * HH) / 1024, 256, 0, stream>>>(hidden, hidden_bf);
    cast_f2b<<<(2 * II * HH) / 1024, 256, 0, stream>>>(in_proj_w, inw_bf);

    // 2) in_proj MFMA: de-interleave even/odd o -> xraw, gate
    gemm_mfma<0><<<dim3(8192 / 128, BSF / 128), 256, 0, stream>>>(
        hidden_bf, inw_bf, xraw, gate, HH, II);

    // 3) cast out_proj_w into the (now free) inw slot
    cast_f2b<<<(HH * II) / 1024, 256, 0, stream>>>(out_proj_w, outw_bf);

    // 4) depthwise causal conv + SiLU
    conv_silu_kernel<<<(BSF * II) / 256, 256, 0, stream>>>(xraw, conv_w, conv_b, xsb);

    // 5) x_proj: ssm[h][(b,s)][r] = x_proj_w[h] . xs[h]^T  (M=160, K=2048)
    gemm_small<float, bf16, float, 0><<<dim3(BSF / 64, 3, NHH), 256, 0, stream>>>(
        x_proj_w, HDD, (long)RN2 * HDD,
        xsb, II, (long)HDD,
        ssm, RN2, (long)BSF * RN2,
        nullptr, 0, RN2, HDD);

    // 6) dt: dtb[(b,s)][h*HD+d] = softplus(dt_proj_w[h] . dt_in + bias)
    gemm_small<float, float, bf16, 1><<<dim3(BSF / 64, HDD / 64, NHH), 256, 0, stream>>>(
        dt_proj_w, RR, (long)HDD * RR,
        ssm, RN2, (long)BSF * RN2,
        dtb, II, (long)HDD,
        dt_proj_b, (long)HDD,
        HDD, RR);

    // 7) selective scan + D skip + SiLU gating -> yfin (b*s, i)
    scan_kernel<<<32, 256, 0, stream>>>(dtb, xsb, gate, ssm, A_log, Dp, yfin);

    // 8) out_proj MFMA: out[(b,s)][h'] = yfin . out_proj_w^T (fp32 store)
    gemm_mfma<1><<<dim3(HH / 128, BSF / 128), 256, 0, stream>>>(
        yfin, outw_bf, out, nullptr, II, HH);
}